// Round 18
// baseline (1926.827 us; speedup 1.0000x reference)
//
#include <hip/hip_runtime.h>
#include <hip/hip_bf16.h>
#include <float.h>

#define NPTS 2048
#define KNBR 20
#define CATC 512

__device__ __forceinline__ float lrelu(float s){ return s >= 0.f ? s : 0.2f*s; }

// ---------------------------------------------------------------------------
// Per-wave register-resident top-20 of pdw[0..2048). Barrier-free.
// ---------------------------------------------------------------------------
__device__ __forceinline__ void argmax20_reg(const float* pdw,
                                             int* __restrict__ idx_out, long row)
{
    const int lane = threadIdx.x & 63;
    float p[32];
#pragma unroll
    for (int e = 0; e < 32; ++e) p[e] = pdw[lane + 64*e];

    float lv = p[0]; int le = 0;
#pragma unroll
    for (int e = 1; e < 32; ++e) if (p[e] > lv) { lv = p[e]; le = e; }

    int myIdx = 0;
    for (int it = 0; it < KNBR; ++it) {
        float gv = lv; int gj = lane + (le << 6);
#pragma unroll
        for (int off = 1; off < 64; off <<= 1) {
            float ov = __shfl_xor(gv, off);
            int   oj = __shfl_xor(gj, off);
            if (ov > gv || (ov == gv && oj < gj)) { gv = ov; gj = oj; }
        }
        if (it == lane) myIdx = gj;
        if ((gj & 63) == lane) {
            int ge = gj >> 6;
#pragma unroll
            for (int e = 0; e < 32; ++e) if (e == ge) p[e] = -FLT_MAX;
            lv = p[0]; le = 0;
#pragma unroll
            for (int e = 1; e < 32; ++e) if (p[e] > lv) { lv = p[e]; le = e; }
        }
    }
    if (lane < KNBR) idx_out[row * KNBR + lane] = myIdx;
}

// ---------------------------------------------------------------------------
// Layer-1 topk: x (B,3,N) fp32. 4 centers per block (one per wave).
// ---------------------------------------------------------------------------
__global__ __launch_bounds__(256)
void topk_x_kernel(const float* __restrict__ x, int* __restrict__ idx_out)
{
    __shared__ __align__(16) float pd[4][NPTS];
    __shared__ float ctr[4][3];
    const int blk = blockIdx.x;               // 4096 = 8 * 512
    const int b = blk >> 9;
    const int n0 = (blk & 511) << 2;
    const int tid = threadIdx.x;
    const float* base = x + (long)b * 3 * NPTS;

    if (tid < 16) {
        int w = tid >> 2, c = tid & 3;
        if (c < 3) ctr[w][c] = base[c * NPTS + n0 + w];
    }
    __syncthreads();

    for (int j = tid; j < NPTS; j += 256) {
        float v0 = base[j], v1 = base[NPTS + j], v2 = base[2 * NPTS + j];
        float sq = v0*v0 + v1*v1 + v2*v2;
#pragma unroll
        for (int w = 0; w < 4; ++w) {
            float d  = v0*ctr[w][0] + v1*ctr[w][1] + v2*ctr[w][2];
            float sc = ctr[w][0]*ctr[w][0] + ctr[w][1]*ctr[w][1] + ctr[w][2]*ctr[w][2];
            pd[w][j] = 2.f*d - sc - sq;
        }
    }
    __syncthreads();
    argmax20_reg(pd[tid >> 6], idx_out, (long)b * NPTS + n0 + (tid >> 6));
}

// ---------------------------------------------------------------------------
// Per-point squared norm over C channels at chanOff (order-matched).
// ---------------------------------------------------------------------------
template<int C>
__global__ __launch_bounds__(256)
void norm_kernel(const float* __restrict__ feat, int chanOff,
                 float* __restrict__ norms)
{
    int gid = blockIdx.x * 256 + threadIdx.x;   // 0..16383 = b*NPTS + n
    const float4* p = (const float4*)(feat + (long)gid * CATC + chanOff);
    float s = 0.f;
#pragma unroll
    for (int q = 0; q < C / 4; ++q) {
        float4 r = p[q];
        s += r.x*r.x; s += r.y*r.y; s += r.z*r.z; s += r.w*r.w;
    }
    norms[gid] = s;
}

// ---------------------------------------------------------------------------
// Layer 2-4 topk: 16 centers per block, 1024 threads; dot[16][2] accums.
// ---------------------------------------------------------------------------
template<int C>
__global__ __launch_bounds__(1024)
void topk_feat_kernel(const float* __restrict__ feat, int chanOff,
                      const float* __restrict__ norms,
                      int* __restrict__ idx_out)
{
    __shared__ __align__(16) float pd[16][NPTS];   // 128 KB
    const int blk = blockIdx.x;                    // 1024 = 8 * 128
    const int b = blk >> 7;
    const int n0 = (blk & 127) << 4;
    const int tid = threadIdx.x;                   // 0..1023
    const float* base = feat + (long)b * NPTS * CATC + chanOff;
    constexpr int Q = C / 4;

    const float4* c4p[16];
#pragma unroll
    for (int w = 0; w < 16; ++w)
        c4p[w] = (const float4*)(base + (long)(n0 + w) * CATC);

    float sqc[16];
#pragma unroll
    for (int w = 0; w < 16; ++w)
        sqc[w] = norms[(long)b * NPTS + n0 + w];   // uniform -> s_load

    const float* rowBase[2];
    float nrm[2];
#pragma unroll
    for (int k = 0; k < 2; ++k) {
        rowBase[k] = base + (long)(tid + 1024 * k) * CATC;
        nrm[k] = norms[(long)b * NPTS + tid + 1024 * k];
    }

    float dot[16][2];
#pragma unroll
    for (int w = 0; w < 16; ++w)
#pragma unroll
        for (int k = 0; k < 2; ++k) dot[w][k] = 0.f;

    for (int q = 0; q < Q; ++q) {
        float4 r[2];
#pragma unroll
        for (int k = 0; k < 2; ++k)
            r[k] = *(const float4*)(rowBase[k] + q * 4);
#pragma unroll
        for (int w = 0; w < 16; ++w) {
            float4 cw = c4p[w][q];    // block-uniform -> scalar load
#pragma unroll
            for (int k = 0; k < 2; ++k) {
                dot[w][k] += r[k].x * cw.x;
                dot[w][k] += r[k].y * cw.y;
                dot[w][k] += r[k].z * cw.z;
                dot[w][k] += r[k].w * cw.w;
            }
        }
    }

#pragma unroll
    for (int k = 0; k < 2; ++k)
#pragma unroll
        for (int w = 0; w < 16; ++w)
            pd[w][tid + 1024*k] = 2.f*dot[w][k] - sqc[w] - nrm[k];
    __syncthreads();
    argmax20_reg(pd[tid >> 6], idx_out, (long)b * NPTS + n0 + (tid >> 6));
}

// ---------------------------------------------------------------------------
// Layer-1 EdgeConv: x fp32 (B,3,N) -> feat ch 0..63 (fp32).
// ---------------------------------------------------------------------------
__global__ __launch_bounds__(64)
void edgeconv_x_kernel(const float* __restrict__ x, const int* __restrict__ idx,
                       const float* __restrict__ W, const float* __restrict__ g,
                       const float* __restrict__ bb, float* __restrict__ feat)
{
    __shared__ float ctr[3];
    __shared__ float nd[KNBR * 3];
    __shared__ int jj[KNBR];
    const int row = blockIdx.x;
    const int b = row >> 11, n = row & (NPTS - 1);
    const int tid = threadIdx.x;
    const float* base = x + (long)b * 3 * NPTS;
    if (tid < 3)    ctr[tid] = base[tid * NPTS + n];
    if (tid < KNBR) jj[tid]  = idx[(long)row * KNBR + tid];
    __syncthreads();
    if (tid < KNBR * 3) {
        int kk = tid / 3, c = tid - kk * 3;
        nd[tid] = base[c * NPTS + jj[kk]] - ctr[c];
    }
    __syncthreads();

    const float* wr = W + tid * 6;      // o = tid, W1 (64,6)
    float basev = wr[3]*ctr[0] + wr[4]*ctr[1] + wr[5]*ctr[2];
    float scale = g[tid] * rsqrtf(1.f + 1e-5f);
    float bias  = bb[tid];
    float m = -FLT_MAX;
#pragma unroll
    for (int kk = 0; kk < KNBR; ++kk) {
        float s = basev + wr[0]*nd[kk*3] + wr[1]*nd[kk*3+1] + wr[2]*nd[kk*3+2];
        m = fmaxf(m, lrelu(s * scale + bias));
    }
    feat[((long)b * NPTS + n) * CATC + tid] = m;
}

// ---------------------------------------------------------------------------
// GEMM path, kernel 1: GH[n][0:O] = W[:,0:C]·f(n), GH[n][O:2O] = W[:,C:2C]·f(n)
// ---------------------------------------------------------------------------
template<int C, int O>
__global__ __launch_bounds__(256)
void gemm_gh_kernel(const float* __restrict__ feat, int chanIn,
                    const float* __restrict__ W, float* __restrict__ GH)
{
    __shared__ __align__(16) float Ws[64][C + 4];
    __shared__ __align__(16) float Cs[32][C + 4];
    const int mt = blockIdx.x, ot = blockIdx.y;
    const int tid = threadIdx.x;
    const int ol = tid & 63, ng = tid >> 6;
    const int side = (ot * 64) >= O;   // 0 -> G (W[:,0:C]); 1 -> H (W[:,C:2C])

    for (int t = tid; t < 64 * (C / 4); t += 256) {
        int olr = t / (C / 4), q = t - olr * (C / 4);
        int o = ot * 64 + olr - (side ? O : 0);
        *(float4*)&Ws[olr][q * 4] =
            *(const float4*)&W[(long)o * 2 * C + (side ? C : 0) + q * 4];
    }
    for (int t = tid; t < 32 * (C / 4); t += 256) {
        int nl = t / (C / 4), q = t - nl * (C / 4);
        *(float4*)&Cs[nl][q * 4] =
            *(const float4*)&feat[(long)(mt * 32 + nl) * CATC + chanIn + q * 4];
    }
    __syncthreads();

    float acc[8];
#pragma unroll
    for (int i = 0; i < 8; ++i) acc[i] = 0.f;
    for (int k4 = 0; k4 < C / 4; ++k4) {
        float4 w = *(const float4*)&Ws[ol][k4 * 4];
#pragma unroll
        for (int i = 0; i < 8; ++i) {
            float4 c = *(const float4*)&Cs[ng * 8 + i][k4 * 4];
            acc[i] += w.x*c.x + w.y*c.y + w.z*c.z + w.w*c.w;
        }
    }
#pragma unroll
    for (int i = 0; i < 8; ++i)
        GH[(long)(mt * 32 + ng * 8 + i) * (2 * O) + ot * 64 + ol] = acc[i];
}

// ---------------------------------------------------------------------------
// GEMM path, kernel 2: per point n, m[o] = max_kk lrelu((H[n][o]-G[n][o]
//   + G[j_kk][o])*scale + bias); write feat[n][chanOut+o].
// ---------------------------------------------------------------------------
template<int O, int OPT>
__global__ __launch_bounds__(256)
void gathermax_kernel(const float* __restrict__ GH, const int* __restrict__ idx,
                      const float* __restrict__ g, const float* __restrict__ bb,
                      float* __restrict__ featOut, int chanOut)
{
    const int tid = threadIdx.x;
    const int row = blockIdx.x * 4 + (tid >> 6);   // b*NPTS + n
    const int lane = tid & 63;
    const long ghRow = (long)row * (2 * O);
    const long bBase = (long)(row & ~(NPTS - 1)) * (2 * O);
    const float inv = rsqrtf(1.f + 1e-5f);

    int j[KNBR];
#pragma unroll
    for (int i = 0; i < KNBR; ++i) j[i] = idx[(long)row * KNBR + i];

    float base2[OPT], m[OPT], scale[OPT], bias[OPT];
#pragma unroll
    for (int oi = 0; oi < OPT; ++oi) {
        int o = lane + 64 * oi;
        base2[oi] = GH[ghRow + O + o] - GH[ghRow + o];
        scale[oi] = g[o] * inv;
        bias[oi]  = bb[o];
        m[oi] = -FLT_MAX;
    }
#pragma unroll
    for (int kk = 0; kk < KNBR; ++kk) {
        const float* gr = GH + bBase + (long)j[kk] * (2 * O);
#pragma unroll
        for (int oi = 0; oi < OPT; ++oi) {
            float v = base2[oi] + gr[lane + 64 * oi];
            m[oi] = fmaxf(m[oi], lrelu(v * scale[oi] + bias[oi]));
        }
    }
#pragma unroll
    for (int oi = 0; oi < OPT; ++oi)
        featOut[(long)row * CATC + chanOut + lane + 64 * oi] = m[oi];
}

// ---------------------------------------------------------------------------
// Fallback (small ws): r14 edgeconv — 128 threads, 2 points per block.
// ---------------------------------------------------------------------------
template<int C, int OPT>
__global__ __launch_bounds__(128)
void edgeconv_feat_kernel(const float* __restrict__ featIn, int chanIn,
                          const int* __restrict__ idx,
                          const float* __restrict__ W, const float* __restrict__ g,
                          const float* __restrict__ bb,
                          float* __restrict__ featOut, int chanOut)
{
    __shared__ float ctr[2][C];
    __shared__ __align__(16) float nd[2][KNBR * C];
    __shared__ int jj[2][KNBR];
    const int blk = blockIdx.x;             // 8192 = 8 * 1024
    const int b = blk >> 10;
    const int n0 = (blk & 1023) << 1;
    const int tid = threadIdx.x;
    const int wv = tid >> 6, lane = tid & 63;
    const int n = n0 + wv;
    const long row = (long)b * NPTS + n;
    const float* base = featIn + (long)b * NPTS * CATC + chanIn;

    if (lane < KNBR) jj[wv][lane] = idx[row * KNBR + lane];
    for (int c = lane; c < C; c += 64) ctr[wv][c] = base[(long)n * CATC + c];
    __syncthreads();

    for (int t = lane; t < KNBR * (C / 4); t += 64) {
        int kk = t / (C / 4), q = t - kk * (C / 4);
        float4 r = ((const float4*)(base + (long)jj[wv][kk] * CATC))[q];
        float* dst = &nd[wv][kk * C + q * 4];
        const float* cc = &ctr[wv][q * 4];
        dst[0] = r.x - cc[0]; dst[1] = r.y - cc[1];
        dst[2] = r.z - cc[2]; dst[3] = r.w - cc[3];
    }
    __syncthreads();

    float acc[OPT][KNBR];
#pragma unroll
    for (int oi = 0; oi < OPT; ++oi) {
        const float* wr = W + (long)(lane + 64*oi) * 2 * C + C;
        float basev = 0.f;
#pragma unroll
        for (int c = 0; c < C; ++c) basev += wr[c] * ctr[wv][c];
#pragma unroll
        for (int kk = 0; kk < KNBR; ++kk) acc[oi][kk] = basev;
    }

    const float4* nd4 = (const float4*)nd[wv];
    for (int c4 = 0; c4 < C / 4; ++c4) {
        float4 w[OPT];
#pragma unroll
        for (int oi = 0; oi < OPT; ++oi) {
            const float* wp = W + (long)(lane + 64*oi) * 2 * C + c4 * 4;
            w[oi] = make_float4(wp[0], wp[1], wp[2], wp[3]);
        }
#pragma unroll
        for (int kk = 0; kk < KNBR; ++kk) {
            float4 d = nd4[kk * (C / 4) + c4];
#pragma unroll
            for (int oi = 0; oi < OPT; ++oi)
                acc[oi][kk] += w[oi].x*d.x + w[oi].y*d.y + w[oi].z*d.z + w[oi].w*d.w;
        }
    }

    const float inv = rsqrtf(1.f + 1e-5f);
#pragma unroll
    for (int oi = 0; oi < OPT; ++oi) {
        int o = lane + 64 * oi;
        float scale = g[o] * inv, bias = bb[o];
        float m = -FLT_MAX;
#pragma unroll
        for (int kk = 0; kk < KNBR; ++kk)
            m = fmaxf(m, lrelu(acc[oi][kk] * scale + bias));
        featOut[row * CATC + chanOut + o] = m;
    }
}

// ---------------------------------------------------------------------------
// x5 = lrelu(bn(W5 @ cat)) with fused pooling partials.
// Block covers 128 o x 256 n (8 subtiles of 32 n). Per thread: 2 o x 8 n
// (o = ot*128 + ol + 64*oi). Same access patterns as r15 (Ws lane-row reads,
// Cs wave-broadcast reads) with one extra Ws row -> per k4: 10 ds_read_b128
// feed 64 FMAs (r15: 9 feed 32). K-accumulation order per (o,n) unchanged
// -> x5 bit-identical.
// ---------------------------------------------------------------------------
__global__ __launch_bounds__(256)
void x5_kernel(const float* __restrict__ feat, const float* __restrict__ W5,
               const float* __restrict__ g5, const float* __restrict__ b5,
               float* __restrict__ pmax, float* __restrict__ psum)
{
    __shared__ __align__(16) float Ws[128][36];
    __shared__ __align__(16) float Cs[32][36];
    __shared__ float redm[128][4];
    __shared__ float reds[128][4];
    const int tid = threadIdx.x;
    const int nt = blockIdx.x, ot = blockIdx.y, b = blockIdx.z;
    const int ol = tid & 63, ng = tid >> 6;
    const float inv = rsqrtf(1.f + 1e-5f);

    float scale[2], bias[2];
#pragma unroll
    for (int oi = 0; oi < 2; ++oi) {
        int o = ot * 128 + ol + 64 * oi;
        scale[oi] = g5[o] * inv;
        bias[oi]  = b5[o];
    }

    float gm = -FLT_MAX, gs = 0.f;   // valid for tid < 128 after reductions

    for (int s = 0; s < 8; ++s) {
        float acc[2][8];
#pragma unroll
        for (int oi = 0; oi < 2; ++oi)
#pragma unroll
            for (int i = 0; i < 8; ++i) acc[oi][i] = 0.f;
        const int nBase = nt * 256 + s * 32;

        for (int kb = 0; kb < 16; ++kb) {
#pragma unroll
            for (int t = tid; t < 1024; t += 256) {
                int r = t >> 3, q = t & 7;
                *(float4*)&Ws[r][q*4] =
                    *(const float4*)&W5[(long)(ot*128 + r) * CATC + kb*32 + q*4];
            }
            {
                int nl = tid >> 3, q = tid & 7;
                *(float4*)&Cs[nl][q*4] =
                    *(const float4*)&feat[((long)b*NPTS + nBase + nl)*CATC + kb*32 + q*4];
            }
            __syncthreads();
#pragma unroll
            for (int k4 = 0; k4 < 8; ++k4) {
                float4 w0 = *(const float4*)&Ws[ol][k4*4];
                float4 w1 = *(const float4*)&Ws[ol + 64][k4*4];
#pragma unroll
                for (int i = 0; i < 8; ++i) {
                    float4 c4 = *(const float4*)&Cs[ng*8 + i][k4*4];
                    acc[0][i] += w0.x*c4.x + w0.y*c4.y + w0.z*c4.z + w0.w*c4.w;
                    acc[1][i] += w1.x*c4.x + w1.y*c4.y + w1.z*c4.z + w1.w*c4.w;
                }
            }
            __syncthreads();
        }
        // epilogue for this 32-n subtile
#pragma unroll
        for (int oi = 0; oi < 2; ++oi) {
            float vm = -FLT_MAX, vs = 0.f;
#pragma unroll
            for (int i = 0; i < 8; ++i) {
                float v = lrelu(acc[oi][i] * scale[oi] + bias[oi]);
                vm = fmaxf(vm, v);
                vs += v;
            }
            redm[ol + 64*oi][ng] = vm;
            reds[ol + 64*oi][ng] = vs;
        }
        __syncthreads();
        if (tid < 128) {
            float m = redm[tid][0], sm = reds[tid][0];
#pragma unroll
            for (int w = 1; w < 4; ++w) { m = fmaxf(m, redm[tid][w]); sm += reds[tid][w]; }
            gm = fmaxf(gm, m);
            gs += sm;
        }
        __syncthreads();
    }
    if (tid < 128) {
        long p = ((long)b * 1024 + ot * 128 + tid) * 8 + nt;
        pmax[p] = gm;
        psum[p] = gs;
    }
}

// Reduce 8 partials per (b,o) -> xm/xa; write map2 (fp32) + map_ output (fp32).
__global__ __launch_bounds__(256)
void reduce8_kernel(const float* __restrict__ pmax, const float* __restrict__ psum,
                    float* __restrict__ map2, float* __restrict__ out_map)
{
    int gid = blockIdx.x * 256 + threadIdx.x;   // 8192 = 8*1024
    int b = gid >> 10, o = gid & 1023;
    float m = -FLT_MAX, s = 0.f;
#pragma unroll
    for (int t = 0; t < 8; ++t) {
        m = fmaxf(m, pmax[(long)gid * 8 + t]);
        s += psum[(long)gid * 8 + t];
    }
    float xa = s * (1.f / NPTS);
    map2[(long)b * 2080 + o]        = m;
    map2[(long)b * 2080 + 1024 + o] = xa;
    out_map[(long)b * 2048 + o]        = m;
    out_map[(long)b * 2048 + 1024 + o] = xa;
}

// p1 = lrelu(bn(posefeat @ Wp.T + bp)) -> map2[:, 2048:2080]
__global__ void pose_kernel(const float* __restrict__ pf, const float* __restrict__ Wp,
                            const float* __restrict__ bp, const float* __restrict__ gp,
                            const float* __restrict__ bpb, float* __restrict__ map2)
{
    int t = threadIdx.x;
    if (t < 256) {
        int b = t >> 5, o = t & 31;
        float s = 0.f;
#pragma unroll
        for (int c = 0; c < 6; ++c) s += pf[b*6 + c] * Wp[o*6 + c];
        s += bp[o];
        s = s * (gp[o] * rsqrtf(1.f + 1e-5f)) + bpb[o];
        map2[(long)b * 2080 + 2048 + o] = lrelu(s);
    }
}

// Generic FC: one wave per (b,o). fp32 output.
__global__ __launch_bounds__(64)
void fc_kernel(const float* __restrict__ in, int inStride, int Kdim,
               const float* __restrict__ W, const float* __restrict__ bias,
               const float* __restrict__ g, const float* __restrict__ bbn,
               int Nout, float* __restrict__ outF, int outStride)
{
    int bo = blockIdx.x;
    int b = bo / Nout, o = bo - b * Nout;
    int lane = threadIdx.x;
    const float* inr = in + (long)b * inStride;
    const float* wr  = W + (long)o * Kdim;
    float s = 0.f;
    for (int c = lane; c < Kdim; c += 64) s += inr[c] * wr[c];
#pragma unroll
    for (int off = 32; off; off >>= 1) s += __shfl_down(s, off);
    if (lane == 0) {
        s += bias[o];
        if (g) {
            s = s * (g[o] * rsqrtf(1.f + 1e-5f)) + bbn[o];
            s = lrelu(s);
        }
        outF[(long)b * outStride + o] = s;
    }
}

extern "C" void kernel_launch(void* const* d_in, const int* in_sizes, int n_in,
                              void* d_out, int out_size, void* d_ws, size_t ws_size,
                              hipStream_t stream)
{
    const float* x   = (const float*)d_in[0];
    const float* pf  = (const float*)d_in[1];
    const float *W1 = (const float*)d_in[2],  *g1 = (const float*)d_in[3],  *b1 = (const float*)d_in[4];
    const float *W2 = (const float*)d_in[5],  *g2 = (const float*)d_in[6],  *b2 = (const float*)d_in[7];
    const float *W3 = (const float*)d_in[8],  *g3 = (const float*)d_in[9],  *b3 = (const float*)d_in[10];
    const float *W4 = (const float*)d_in[11], *g4 = (const float*)d_in[12], *b4 = (const float*)d_in[13];
    const float *W5 = (const float*)d_in[14], *g5 = (const float*)d_in[15], *b5 = (const float*)d_in[16];
    const float *Wp = (const float*)d_in[17], *bp = (const float*)d_in[18];
    const float *gp = (const float*)d_in[19], *bpb = (const float*)d_in[20];
    const float *WL1 = (const float*)d_in[21], *bL1 = (const float*)d_in[22];
    const float *g6  = (const float*)d_in[23], *b6  = (const float*)d_in[24];
    const float *WL2 = (const float*)d_in[25], *bL2 = (const float*)d_in[26];
    const float *g7  = (const float*)d_in[27], *b7  = (const float*)d_in[28];
    const float *WL3 = (const float*)d_in[29], *bL3 = (const float*)d_in[30];

    // workspace layout (bytes) — identical to round 15:
    char* wsb = (char*)d_ws;
    float* feat  = (float*)wsb;
    int*   idx   = (int*)(wsb + 33554432);
    float* pmax  = (float*)(wsb + 34865152);
    float* psum  = (float*)(wsb + 35127296);
    float* map2  = (float*)(wsb + 35389440);
    float* h1    = (float*)(wsb + 35456000);
    float* h2    = (float*)(wsb + 35472384);
    float* norms = (float*)(wsb + 35480576);
    float* GH    = (float*)(wsb + 35546112);
    const bool gemmPath = (ws_size >= (size_t)35546112 + 33554432);

    // FP32 output, return order: logits (8,40) then map_ (8,2048).
    float* out        = (float*)d_out;
    float* out_logits = out;
    float* out_map    = out + 320;

    const int rows = 8 * NPTS;      // 16384
    const int tkblk16 = rows / 16;  // 1024 (16 centers per topk block)
    const int gmblk   = rows / 4;   // 4096 (4 points per gathermax block)

    // layer 1: C=3 -> 64 (feat ch 0..63)
    topk_x_kernel<<<rows / 4, 256, 0, stream>>>(x, idx);
    edgeconv_x_kernel<<<rows, 64, 0, stream>>>(x, idx, W1, g1, b1, feat);

    // layer 2: C=64 (ch 0..63) -> 64 (ch 64..127)
    norm_kernel<64><<<64, 256, 0, stream>>>(feat, 0, norms);
    topk_feat_kernel<64><<<tkblk16, 1024, 0, stream>>>(feat, 0, norms, idx);
    if (gemmPath) {
        gemm_gh_kernel<64, 64><<<dim3(512, 2), 256, 0, stream>>>(feat, 0, W2, GH);
        gathermax_kernel<64, 1><<<gmblk, 256, 0, stream>>>(GH, idx, g2, b2, feat, 64);
    } else {
        edgeconv_feat_kernel<64, 1><<<rows / 2, 128, 0, stream>>>(feat, 0, idx, W2, g2, b2, feat, 64);
    }

    // layer 3: C=64 (ch 64..127) -> 128 (ch 128..255)
    norm_kernel<64><<<64, 256, 0, stream>>>(feat, 64, norms);
    topk_feat_kernel<64><<<tkblk16, 1024, 0, stream>>>(feat, 64, norms, idx);
    if (gemmPath) {
        gemm_gh_kernel<64, 128><<<dim3(512, 4), 256, 0, stream>>>(feat, 64, W3, GH);
        gathermax_kernel<128, 2><<<gmblk, 256, 0, stream>>>(GH, idx, g3, b3, feat, 128);
    } else {
        edgeconv_feat_kernel<64, 2><<<rows / 2, 128, 0, stream>>>(feat, 64, idx, W3, g3, b3, feat, 128);
    }

    // layer 4: C=128 (ch 128..255) -> 256 (ch 256..511)
    norm_kernel<128><<<64, 256, 0, stream>>>(feat, 128, norms);
    topk_feat_kernel<128><<<tkblk16, 1024, 0, stream>>>(feat, 128, norms, idx);
    if (gemmPath) {
        gemm_gh_kernel<128, 256><<<dim3(512, 8), 256, 0, stream>>>(feat, 128, W4, GH);
        gathermax_kernel<256, 4><<<gmblk, 256, 0, stream>>>(GH, idx, g4, b4, feat, 256);
    } else {
        edgeconv_feat_kernel<128, 4><<<rows / 2, 128, 0, stream>>>(feat, 128, idx, W4, g4, b4, feat, 256);
    }

    // x5 + pooling: grid (8 nt, 8 ot of 128 o, 8 b)
    dim3 g5grid(8, 8, 8);
    x5_kernel<<<g5grid, 256, 0, stream>>>(feat, W5, g5, b5, pmax, psum);
    reduce8_kernel<<<32, 256, 0, stream>>>(pmax, psum, map2, out_map);

    // head
    pose_kernel<<<1, 256, 0, stream>>>(pf, Wp, bp, gp, bpb, map2);
    fc_kernel<<<8 * 512, 64, 0, stream>>>(map2, 2080, 2080, WL1, bL1, g6, b6, 512, h1, 512);
    fc_kernel<<<8 * 256, 64, 0, stream>>>(h1, 512, 512, WL2, bL2, g7, b7, 256, h2, 256);
    fc_kernel<<<8 * 40, 64, 0, stream>>>(h2, 256, 256, WL3, bL3, nullptr, nullptr, 40, out_logits, 40);
}

// Round 20
// 1824.175 us; speedup vs baseline: 1.0563x; 1.0563x over previous
//
#include <hip/hip_runtime.h>
#include <hip/hip_bf16.h>
#include <float.h>

#define NPTS 2048
#define KNBR 20
#define CATC 512

__device__ __forceinline__ float lrelu(float s){ return s >= 0.f ? s : 0.2f*s; }

// ---------------------------------------------------------------------------
// Per-wave register-resident top-20 of pdw[0..2048). Barrier-free.
// ---------------------------------------------------------------------------
__device__ __forceinline__ void argmax20_reg(const float* pdw,
                                             int* __restrict__ idx_out, long row)
{
    const int lane = threadIdx.x & 63;
    float p[32];
#pragma unroll
    for (int e = 0; e < 32; ++e) p[e] = pdw[lane + 64*e];

    float lv = p[0]; int le = 0;
#pragma unroll
    for (int e = 1; e < 32; ++e) if (p[e] > lv) { lv = p[e]; le = e; }

    int myIdx = 0;
    for (int it = 0; it < KNBR; ++it) {
        float gv = lv; int gj = lane + (le << 6);
#pragma unroll
        for (int off = 1; off < 64; off <<= 1) {
            float ov = __shfl_xor(gv, off);
            int   oj = __shfl_xor(gj, off);
            if (ov > gv || (ov == gv && oj < gj)) { gv = ov; gj = oj; }
        }
        if (it == lane) myIdx = gj;
        if ((gj & 63) == lane) {
            int ge = gj >> 6;
#pragma unroll
            for (int e = 0; e < 32; ++e) if (e == ge) p[e] = -FLT_MAX;
            lv = p[0]; le = 0;
#pragma unroll
            for (int e = 1; e < 32; ++e) if (p[e] > lv) { lv = p[e]; le = e; }
        }
    }
    if (lane < KNBR) idx_out[row * KNBR + lane] = myIdx;
}

// ---------------------------------------------------------------------------
// Layer-1 topk: x (B,3,N) fp32. 4 centers per block (one per wave).
// ---------------------------------------------------------------------------
__global__ __launch_bounds__(256)
void topk_x_kernel(const float* __restrict__ x, int* __restrict__ idx_out)
{
    __shared__ __align__(16) float pd[4][NPTS];
    __shared__ float ctr[4][3];
    const int blk = blockIdx.x;               // 4096 = 8 * 512
    const int b = blk >> 9;
    const int n0 = (blk & 511) << 2;
    const int tid = threadIdx.x;
    const float* base = x + (long)b * 3 * NPTS;

    if (tid < 16) {
        int w = tid >> 2, c = tid & 3;
        if (c < 3) ctr[w][c] = base[c * NPTS + n0 + w];
    }
    __syncthreads();

    for (int j = tid; j < NPTS; j += 256) {
        float v0 = base[j], v1 = base[NPTS + j], v2 = base[2 * NPTS + j];
        float sq = v0*v0 + v1*v1 + v2*v2;
#pragma unroll
        for (int w = 0; w < 4; ++w) {
            float d  = v0*ctr[w][0] + v1*ctr[w][1] + v2*ctr[w][2];
            float sc = ctr[w][0]*ctr[w][0] + ctr[w][1]*ctr[w][1] + ctr[w][2]*ctr[w][2];
            pd[w][j] = 2.f*d - sc - sq;
        }
    }
    __syncthreads();
    argmax20_reg(pd[tid >> 6], idx_out, (long)b * NPTS + n0 + (tid >> 6));
}

// ---------------------------------------------------------------------------
// Per-point squared norm over C channels at chanOff (order-matched).
// ---------------------------------------------------------------------------
template<int C>
__global__ __launch_bounds__(256)
void norm_kernel(const float* __restrict__ feat, int chanOff,
                 float* __restrict__ norms)
{
    int gid = blockIdx.x * 256 + threadIdx.x;   // 0..16383 = b*NPTS + n
    const float4* p = (const float4*)(feat + (long)gid * CATC + chanOff);
    float s = 0.f;
#pragma unroll
    for (int q = 0; q < C / 4; ++q) {
        float4 r = p[q];
        s += r.x*r.x; s += r.y*r.y; s += r.z*r.z; s += r.w*r.w;
    }
    norms[gid] = s;
}

// ---------------------------------------------------------------------------
// Layer 2-4 topk: 16 centers per block, 1024 threads; dot[16][2] accums.
// ---------------------------------------------------------------------------
template<int C>
__global__ __launch_bounds__(1024)
void topk_feat_kernel(const float* __restrict__ feat, int chanOff,
                      const float* __restrict__ norms,
                      int* __restrict__ idx_out)
{
    __shared__ __align__(16) float pd[16][NPTS];   // 128 KB
    const int blk = blockIdx.x;                    // 1024 = 8 * 128
    const int b = blk >> 7;
    const int n0 = (blk & 127) << 4;
    const int tid = threadIdx.x;                   // 0..1023
    const float* base = feat + (long)b * NPTS * CATC + chanOff;
    constexpr int Q = C / 4;

    const float4* c4p[16];
#pragma unroll
    for (int w = 0; w < 16; ++w)
        c4p[w] = (const float4*)(base + (long)(n0 + w) * CATC);

    float sqc[16];
#pragma unroll
    for (int w = 0; w < 16; ++w)
        sqc[w] = norms[(long)b * NPTS + n0 + w];   // uniform -> s_load

    const float* rowBase[2];
    float nrm[2];
#pragma unroll
    for (int k = 0; k < 2; ++k) {
        rowBase[k] = base + (long)(tid + 1024 * k) * CATC;
        nrm[k] = norms[(long)b * NPTS + tid + 1024 * k];
    }

    float dot[16][2];
#pragma unroll
    for (int w = 0; w < 16; ++w)
#pragma unroll
        for (int k = 0; k < 2; ++k) dot[w][k] = 0.f;

    for (int q = 0; q < Q; ++q) {
        float4 r[2];
#pragma unroll
        for (int k = 0; k < 2; ++k)
            r[k] = *(const float4*)(rowBase[k] + q * 4);
#pragma unroll
        for (int w = 0; w < 16; ++w) {
            float4 cw = c4p[w][q];    // block-uniform -> scalar load
#pragma unroll
            for (int k = 0; k < 2; ++k) {
                dot[w][k] += r[k].x * cw.x;
                dot[w][k] += r[k].y * cw.y;
                dot[w][k] += r[k].z * cw.z;
                dot[w][k] += r[k].w * cw.w;
            }
        }
    }

#pragma unroll
    for (int k = 0; k < 2; ++k)
#pragma unroll
        for (int w = 0; w < 16; ++w)
            pd[w][tid + 1024*k] = 2.f*dot[w][k] - sqc[w] - nrm[k];
    __syncthreads();
    argmax20_reg(pd[tid >> 6], idx_out, (long)b * NPTS + n0 + (tid >> 6));
}

// ---------------------------------------------------------------------------
// Layer-1 EdgeConv: x fp32 (B,3,N) -> feat ch 0..63 (fp32).
// ---------------------------------------------------------------------------
__global__ __launch_bounds__(64)
void edgeconv_x_kernel(const float* __restrict__ x, const int* __restrict__ idx,
                       const float* __restrict__ W, const float* __restrict__ g,
                       const float* __restrict__ bb, float* __restrict__ feat)
{
    __shared__ float ctr[3];
    __shared__ float nd[KNBR * 3];
    __shared__ int jj[KNBR];
    const int row = blockIdx.x;
    const int b = row >> 11, n = row & (NPTS - 1);
    const int tid = threadIdx.x;
    const float* base = x + (long)b * 3 * NPTS;
    if (tid < 3)    ctr[tid] = base[tid * NPTS + n];
    if (tid < KNBR) jj[tid]  = idx[(long)row * KNBR + tid];
    __syncthreads();
    if (tid < KNBR * 3) {
        int kk = tid / 3, c = tid - kk * 3;
        nd[tid] = base[c * NPTS + jj[kk]] - ctr[c];
    }
    __syncthreads();

    const float* wr = W + tid * 6;      // o = tid, W1 (64,6)
    float basev = wr[3]*ctr[0] + wr[4]*ctr[1] + wr[5]*ctr[2];
    float scale = g[tid] * rsqrtf(1.f + 1e-5f);
    float bias  = bb[tid];
    float m = -FLT_MAX;
#pragma unroll
    for (int kk = 0; kk < KNBR; ++kk) {
        float s = basev + wr[0]*nd[kk*3] + wr[1]*nd[kk*3+1] + wr[2]*nd[kk*3+2];
        m = fmaxf(m, lrelu(s * scale + bias));
    }
    feat[((long)b * NPTS + n) * CATC + tid] = m;
}

// ---------------------------------------------------------------------------
// GEMM path, kernel 1: GH[n][0:O] = W[:,0:C]·f(n), GH[n][O:2O] = W[:,C:2C]·f(n)
// ---------------------------------------------------------------------------
template<int C, int O>
__global__ __launch_bounds__(256)
void gemm_gh_kernel(const float* __restrict__ feat, int chanIn,
                    const float* __restrict__ W, float* __restrict__ GH)
{
    __shared__ __align__(16) float Ws[64][C + 4];
    __shared__ __align__(16) float Cs[32][C + 4];
    const int mt = blockIdx.x, ot = blockIdx.y;
    const int tid = threadIdx.x;
    const int ol = tid & 63, ng = tid >> 6;
    const int side = (ot * 64) >= O;   // 0 -> G (W[:,0:C]); 1 -> H (W[:,C:2C])

    for (int t = tid; t < 64 * (C / 4); t += 256) {
        int olr = t / (C / 4), q = t - olr * (C / 4);
        int o = ot * 64 + olr - (side ? O : 0);
        *(float4*)&Ws[olr][q * 4] =
            *(const float4*)&W[(long)o * 2 * C + (side ? C : 0) + q * 4];
    }
    for (int t = tid; t < 32 * (C / 4); t += 256) {
        int nl = t / (C / 4), q = t - nl * (C / 4);
        *(float4*)&Cs[nl][q * 4] =
            *(const float4*)&feat[(long)(mt * 32 + nl) * CATC + chanIn + q * 4];
    }
    __syncthreads();

    float acc[8];
#pragma unroll
    for (int i = 0; i < 8; ++i) acc[i] = 0.f;
    for (int k4 = 0; k4 < C / 4; ++k4) {
        float4 w = *(const float4*)&Ws[ol][k4 * 4];
#pragma unroll
        for (int i = 0; i < 8; ++i) {
            float4 c = *(const float4*)&Cs[ng * 8 + i][k4 * 4];
            acc[i] += w.x*c.x + w.y*c.y + w.z*c.z + w.w*c.w;
        }
    }
#pragma unroll
    for (int i = 0; i < 8; ++i)
        GH[(long)(mt * 32 + ng * 8 + i) * (2 * O) + ot * 64 + ol] = acc[i];
}

// ---------------------------------------------------------------------------
// GEMM path, kernel 2: per point n, m[o] = max_kk lrelu((H[n][o]-G[n][o]
//   + G[j_kk][o])*scale + bias); write feat[n][chanOut+o].
// ---------------------------------------------------------------------------
template<int O, int OPT>
__global__ __launch_bounds__(256)
void gathermax_kernel(const float* __restrict__ GH, const int* __restrict__ idx,
                      const float* __restrict__ g, const float* __restrict__ bb,
                      float* __restrict__ featOut, int chanOut)
{
    const int tid = threadIdx.x;
    const int row = blockIdx.x * 4 + (tid >> 6);   // b*NPTS + n
    const int lane = tid & 63;
    const long ghRow = (long)row * (2 * O);
    const long bBase = (long)(row & ~(NPTS - 1)) * (2 * O);
    const float inv = rsqrtf(1.f + 1e-5f);

    int j[KNBR];
#pragma unroll
    for (int i = 0; i < KNBR; ++i) j[i] = idx[(long)row * KNBR + i];

    float base2[OPT], m[OPT], scale[OPT], bias[OPT];
#pragma unroll
    for (int oi = 0; oi < OPT; ++oi) {
        int o = lane + 64 * oi;
        base2[oi] = GH[ghRow + O + o] - GH[ghRow + o];
        scale[oi] = g[o] * inv;
        bias[oi]  = bb[o];
        m[oi] = -FLT_MAX;
    }
#pragma unroll
    for (int kk = 0; kk < KNBR; ++kk) {
        const float* gr = GH + bBase + (long)j[kk] * (2 * O);
#pragma unroll
        for (int oi = 0; oi < OPT; ++oi) {
            float v = base2[oi] + gr[lane + 64 * oi];
            m[oi] = fmaxf(m[oi], lrelu(v * scale[oi] + bias[oi]));
        }
    }
#pragma unroll
    for (int oi = 0; oi < OPT; ++oi)
        featOut[(long)row * CATC + chanOut + lane + 64 * oi] = m[oi];
}

// ---------------------------------------------------------------------------
// Fallback (small ws): r14 edgeconv — 128 threads, 2 points per block.
// ---------------------------------------------------------------------------
template<int C, int OPT>
__global__ __launch_bounds__(128)
void edgeconv_feat_kernel(const float* __restrict__ featIn, int chanIn,
                          const int* __restrict__ idx,
                          const float* __restrict__ W, const float* __restrict__ g,
                          const float* __restrict__ bb,
                          float* __restrict__ featOut, int chanOut)
{
    __shared__ float ctr[2][C];
    __shared__ __align__(16) float nd[2][KNBR * C];
    __shared__ int jj[2][KNBR];
    const int blk = blockIdx.x;             // 8192 = 8 * 1024
    const int b = blk >> 10;
    const int n0 = (blk & 1023) << 1;
    const int tid = threadIdx.x;
    const int wv = tid >> 6, lane = tid & 63;
    const int n = n0 + wv;
    const long row = (long)b * NPTS + n;
    const float* base = featIn + (long)b * NPTS * CATC + chanIn;

    if (lane < KNBR) jj[wv][lane] = idx[row * KNBR + lane];
    for (int c = lane; c < C; c += 64) ctr[wv][c] = base[(long)n * CATC + c];
    __syncthreads();

    for (int t = lane; t < KNBR * (C / 4); t += 64) {
        int kk = t / (C / 4), q = t - kk * (C / 4);
        float4 r = ((const float4*)(base + (long)jj[wv][kk] * CATC))[q];
        float* dst = &nd[wv][kk * C + q * 4];
        const float* cc = &ctr[wv][q * 4];
        dst[0] = r.x - cc[0]; dst[1] = r.y - cc[1];
        dst[2] = r.z - cc[2]; dst[3] = r.w - cc[3];
    }
    __syncthreads();

    float acc[OPT][KNBR];
#pragma unroll
    for (int oi = 0; oi < OPT; ++oi) {
        const float* wr = W + (long)(lane + 64*oi) * 2 * C + C;
        float basev = 0.f;
#pragma unroll
        for (int c = 0; c < C; ++c) basev += wr[c] * ctr[wv][c];
#pragma unroll
        for (int kk = 0; kk < KNBR; ++kk) acc[oi][kk] = basev;
    }

    const float4* nd4 = (const float4*)nd[wv];
    for (int c4 = 0; c4 < C / 4; ++c4) {
        float4 w[OPT];
#pragma unroll
        for (int oi = 0; oi < OPT; ++oi) {
            const float* wp = W + (long)(lane + 64*oi) * 2 * C + c4 * 4;
            w[oi] = make_float4(wp[0], wp[1], wp[2], wp[3]);
        }
#pragma unroll
        for (int kk = 0; kk < KNBR; ++kk) {
            float4 d = nd4[kk * (C / 4) + c4];
#pragma unroll
            for (int oi = 0; oi < OPT; ++oi)
                acc[oi][kk] += w[oi].x*d.x + w[oi].y*d.y + w[oi].z*d.z + w[oi].w*d.w;
        }
    }

    const float inv = rsqrtf(1.f + 1e-5f);
#pragma unroll
    for (int oi = 0; oi < OPT; ++oi) {
        int o = lane + 64 * oi;
        float scale = g[o] * inv, bias = bb[o];
        float m = -FLT_MAX;
#pragma unroll
        for (int kk = 0; kk < KNBR; ++kk)
            m = fmaxf(m, lrelu(acc[oi][kk] * scale + bias));
        featOut[row * CATC + chanOut + o] = m;
    }
}

// ---------------------------------------------------------------------------
// x5 = lrelu(bn(W5 @ cat)) with fused pooling partials — round-15 version
// (1 o x 8 n per thread; Cs reads wave-broadcast; known 570 us; 68 VGPR,
// 26.5% occ). r16/r18/r19 variants all regressed or faulted — this is the
// compiler's sweet spot for this loop shape.
// ---------------------------------------------------------------------------
__global__ __launch_bounds__(256)
void x5_kernel(const float* __restrict__ feat, const float* __restrict__ W5,
               const float* __restrict__ g5, const float* __restrict__ b5,
               float* __restrict__ pmax, float* __restrict__ psum)
{
    __shared__ __align__(16) float Ws[64][36];
    __shared__ __align__(16) float Cs[32][36];
    __shared__ float red[64][8];
    const int tid = threadIdx.x;
    const int nt = blockIdx.x, ot = blockIdx.y, b = blockIdx.z;
    const int ol = tid & 63, ng = tid >> 6;
    const int o = ot * 64 + ol;
    const float scale = g5[o] * rsqrtf(1.f + 1e-5f);
    const float bias  = b5[o];

    float gmax = -FLT_MAX, gsum = 0.f;
    for (int s = 0; s < 8; ++s) {
        float acc[8];
#pragma unroll
        for (int i = 0; i < 8; ++i) acc[i] = 0.f;
        const int nBase = nt * 256 + s * 32;

        for (int kb = 0; kb < 16; ++kb) {
#pragma unroll
            for (int t = tid; t < 512; t += 256) {
                int olr = t >> 3, q = t & 7;
                *(float4*)&Ws[olr][q*4] =
                    *(const float4*)&W5[(long)(ot*64 + olr) * CATC + kb*32 + q*4];
            }
            {
                int nl = tid >> 3, q = tid & 7;
                *(float4*)&Cs[nl][q*4] =
                    *(const float4*)&feat[((long)b*NPTS + nBase + nl)*CATC + kb*32 + q*4];
            }
            __syncthreads();
#pragma unroll
            for (int k4 = 0; k4 < 8; ++k4) {
                float4 w = *(const float4*)&Ws[ol][k4*4];
#pragma unroll
                for (int i = 0; i < 8; ++i) {
                    float4 c4 = *(const float4*)&Cs[ng*8 + i][k4*4];
                    acc[i] += w.x*c4.x + w.y*c4.y + w.z*c4.z + w.w*c4.w;
                }
            }
            __syncthreads();
        }
#pragma unroll
        for (int i = 0; i < 8; ++i) {
            float v = lrelu(acc[i] * scale + bias);
            gmax = fmaxf(gmax, v);
            gsum += v;
        }
    }
    red[ol][ng]     = gmax;
    red[ol][4 + ng] = gsum;
    __syncthreads();
    if (tid < 64) {
        float m = red[tid][0], sm = red[tid][4];
#pragma unroll
        for (int w = 1; w < 4; ++w) { m = fmaxf(m, red[tid][w]); sm += red[tid][4 + w]; }
        long p = ((long)b * 1024 + ot * 64 + tid) * 8 + nt;
        pmax[p] = m; psum[p] = sm;
    }
}

// Reduce 8 partials per (b,o) -> xm/xa; write map2 (fp32) + map_ output (fp32).
__global__ __launch_bounds__(256)
void reduce8_kernel(const float* __restrict__ pmax, const float* __restrict__ psum,
                    float* __restrict__ map2, float* __restrict__ out_map)
{
    int gid = blockIdx.x * 256 + threadIdx.x;   // 8192 = 8*1024
    int b = gid >> 10, o = gid & 1023;
    float m = -FLT_MAX, s = 0.f;
#pragma unroll
    for (int t = 0; t < 8; ++t) {
        m = fmaxf(m, pmax[(long)gid * 8 + t]);
        s += psum[(long)gid * 8 + t];
    }
    float xa = s * (1.f / NPTS);
    map2[(long)b * 2080 + o]        = m;
    map2[(long)b * 2080 + 1024 + o] = xa;
    out_map[(long)b * 2048 + o]        = m;
    out_map[(long)b * 2048 + 1024 + o] = xa;
}

// p1 = lrelu(bn(posefeat @ Wp.T + bp)) -> map2[:, 2048:2080]
__global__ void pose_kernel(const float* __restrict__ pf, const float* __restrict__ Wp,
                            const float* __restrict__ bp, const float* __restrict__ gp,
                            const float* __restrict__ bpb, float* __restrict__ map2)
{
    int t = threadIdx.x;
    if (t < 256) {
        int b = t >> 5, o = t & 31;
        float s = 0.f;
#pragma unroll
        for (int c = 0; c < 6; ++c) s += pf[b*6 + c] * Wp[o*6 + c];
        s += bp[o];
        s = s * (gp[o] * rsqrtf(1.f + 1e-5f)) + bpb[o];
        map2[(long)b * 2080 + 2048 + o] = lrelu(s);
    }
}

// Generic FC: one wave per (b,o). fp32 output.
__global__ __launch_bounds__(64)
void fc_kernel(const float* __restrict__ in, int inStride, int Kdim,
               const float* __restrict__ W, const float* __restrict__ bias,
               const float* __restrict__ g, const float* __restrict__ bbn,
               int Nout, float* __restrict__ outF, int outStride)
{
    int bo = blockIdx.x;
    int b = bo / Nout, o = bo - b * Nout;
    int lane = threadIdx.x;
    const float* inr = in + (long)b * inStride;
    const float* wr  = W + (long)o * Kdim;
    float s = 0.f;
    for (int c = lane; c < Kdim; c += 64) s += inr[c] * wr[c];
#pragma unroll
    for (int off = 32; off; off >>= 1) s += __shfl_down(s, off);
    if (lane == 0) {
        s += bias[o];
        if (g) {
            s = s * (g[o] * rsqrtf(1.f + 1e-5f)) + bbn[o];
            s = lrelu(s);
        }
        outF[(long)b * outStride + o] = s;
    }
}

extern "C" void kernel_launch(void* const* d_in, const int* in_sizes, int n_in,
                              void* d_out, int out_size, void* d_ws, size_t ws_size,
                              hipStream_t stream)
{
    const float* x   = (const float*)d_in[0];
    const float* pf  = (const float*)d_in[1];
    const float *W1 = (const float*)d_in[2],  *g1 = (const float*)d_in[3],  *b1 = (const float*)d_in[4];
    const float *W2 = (const float*)d_in[5],  *g2 = (const float*)d_in[6],  *b2 = (const float*)d_in[7];
    const float *W3 = (const float*)d_in[8],  *g3 = (const float*)d_in[9],  *b3 = (const float*)d_in[10];
    const float *W4 = (const float*)d_in[11], *g4 = (const float*)d_in[12], *b4 = (const float*)d_in[13];
    const float *W5 = (const float*)d_in[14], *g5 = (const float*)d_in[15], *b5 = (const float*)d_in[16];
    const float *Wp = (const float*)d_in[17], *bp = (const float*)d_in[18];
    const float *gp = (const float*)d_in[19], *bpb = (const float*)d_in[20];
    const float *WL1 = (const float*)d_in[21], *bL1 = (const float*)d_in[22];
    const float *g6  = (const float*)d_in[23], *b6  = (const float*)d_in[24];
    const float *WL2 = (const float*)d_in[25], *bL2 = (const float*)d_in[26];
    const float *g7  = (const float*)d_in[27], *b7  = (const float*)d_in[28];
    const float *WL3 = (const float*)d_in[29], *bL3 = (const float*)d_in[30];

    // workspace layout (bytes) — identical to round 15:
    char* wsb = (char*)d_ws;
    float* feat  = (float*)wsb;
    int*   idx   = (int*)(wsb + 33554432);
    float* pmax  = (float*)(wsb + 34865152);
    float* psum  = (float*)(wsb + 35127296);
    float* map2  = (float*)(wsb + 35389440);
    float* h1    = (float*)(wsb + 35456000);
    float* h2    = (float*)(wsb + 35472384);
    float* norms = (float*)(wsb + 35480576);
    float* GH    = (float*)(wsb + 35546112);
    const bool gemmPath = (ws_size >= (size_t)35546112 + 33554432);

    // FP32 output, return order: logits (8,40) then map_ (8,2048).
    float* out        = (float*)d_out;
    float* out_logits = out;
    float* out_map    = out + 320;

    const int rows = 8 * NPTS;      // 16384
    const int tkblk16 = rows / 16;  // 1024 (16 centers per topk block)
    const int gmblk   = rows / 4;   // 4096 (4 points per gathermax block)

    // layer 1: C=3 -> 64 (feat ch 0..63)
    topk_x_kernel<<<rows / 4, 256, 0, stream>>>(x, idx);
    edgeconv_x_kernel<<<rows, 64, 0, stream>>>(x, idx, W1, g1, b1, feat);

    // layer 2: C=64 (ch 0..63) -> 64 (ch 64..127)
    norm_kernel<64><<<64, 256, 0, stream>>>(feat, 0, norms);
    topk_feat_kernel<64><<<tkblk16, 1024, 0, stream>>>(feat, 0, norms, idx);
    if (gemmPath) {
        gemm_gh_kernel<64, 64><<<dim3(512, 2), 256, 0, stream>>>(feat, 0, W2, GH);
        gathermax_kernel<64, 1><<<gmblk, 256, 0, stream>>>(GH, idx, g2, b2, feat, 64);
    } else {
        edgeconv_feat_kernel<64, 1><<<rows / 2, 128, 0, stream>>>(feat, 0, idx, W2, g2, b2, feat, 64);
    }

    // layer 3: C=64 (ch 64..127) -> 128 (ch 128..255)
    norm_kernel<64><<<64, 256, 0, stream>>>(feat, 64, norms);
    topk_feat_kernel<64><<<tkblk16, 1024, 0, stream>>>(feat, 64, norms, idx);
    if (gemmPath) {
        gemm_gh_kernel<64, 128><<<dim3(512, 4), 256, 0, stream>>>(feat, 64, W3, GH);
        gathermax_kernel<128, 2><<<gmblk, 256, 0, stream>>>(GH, idx, g3, b3, feat, 128);
    } else {
        edgeconv_feat_kernel<64, 2><<<rows / 2, 128, 0, stream>>>(feat, 64, idx, W3, g3, b3, feat, 128);
    }

    // layer 4: C=128 (ch 128..255) -> 256 (ch 256..511)
    norm_kernel<128><<<64, 256, 0, stream>>>(feat, 128, norms);
    topk_feat_kernel<128><<<tkblk16, 1024, 0, stream>>>(feat, 128, norms, idx);
    if (gemmPath) {
        gemm_gh_kernel<128, 256><<<dim3(512, 8), 256, 0, stream>>>(feat, 128, W4, GH);
        gathermax_kernel<256, 4><<<gmblk, 256, 0, stream>>>(GH, idx, g4, b4, feat, 256);
    } else {
        edgeconv_feat_kernel<128, 4><<<rows / 2, 128, 0, stream>>>(feat, 128, idx, W4, g4, b4, feat, 256);
    }

    // x5 + pooling: grid (8 nt, 16 ot of 64 o, 8 b) — r15 geometry
    dim3 g5grid(8, 16, 8);
    x5_kernel<<<g5grid, 256, 0, stream>>>(feat, W5, g5, b5, pmax, psum);
    reduce8_kernel<<<32, 256, 0, stream>>>(pmax, psum, map2, out_map);

    // head
    pose_kernel<<<1, 256, 0, stream>>>(pf, Wp, bp, gp, bpb, map2);
    fc_kernel<<<8 * 512, 64, 0, stream>>>(map2, 2080, 2080, WL1, bL1, g6, b6, 512, h1, 512);
    fc_kernel<<<8 * 256, 64, 0, stream>>>(h1, 512, 512, WL2, bL2, g7, b7, 256, h2, 256);
    fc_kernel<<<8 * 40, 64, 0, stream>>>(h2, 256, 256, WL3, bL3, nullptr, nullptr, 40, out_logits, 40);
}

// Round 21
// 1761.488 us; speedup vs baseline: 1.0939x; 1.0356x over previous
//
#include <hip/hip_runtime.h>
#include <hip/hip_bf16.h>
#include <float.h>

#define NPTS 2048
#define KNBR 20
#define CATC 512

__device__ __forceinline__ float lrelu(float s){ return s >= 0.f ? s : 0.2f*s; }

// ---------------------------------------------------------------------------
// Per-wave register-resident top-20 of pdw[0..2048). Barrier-free.
// ---------------------------------------------------------------------------
__device__ __forceinline__ void argmax20_reg(const float* pdw,
                                             int* __restrict__ idx_out, long row)
{
    const int lane = threadIdx.x & 63;
    float p[32];
#pragma unroll
    for (int e = 0; e < 32; ++e) p[e] = pdw[lane + 64*e];

    float lv = p[0]; int le = 0;
#pragma unroll
    for (int e = 1; e < 32; ++e) if (p[e] > lv) { lv = p[e]; le = e; }

    int myIdx = 0;
    for (int it = 0; it < KNBR; ++it) {
        float gv = lv; int gj = lane + (le << 6);
#pragma unroll
        for (int off = 1; off < 64; off <<= 1) {
            float ov = __shfl_xor(gv, off);
            int   oj = __shfl_xor(gj, off);
            if (ov > gv || (ov == gv && oj < gj)) { gv = ov; gj = oj; }
        }
        if (it == lane) myIdx = gj;
        if ((gj & 63) == lane) {
            int ge = gj >> 6;
#pragma unroll
            for (int e = 0; e < 32; ++e) if (e == ge) p[e] = -FLT_MAX;
            lv = p[0]; le = 0;
#pragma unroll
            for (int e = 1; e < 32; ++e) if (p[e] > lv) { lv = p[e]; le = e; }
        }
    }
    if (lane < KNBR) idx_out[row * KNBR + lane] = myIdx;
}

// ---------------------------------------------------------------------------
// Layer-1 topk: x (B,3,N) fp32. 4 centers per block (one per wave).
// ---------------------------------------------------------------------------
__global__ __launch_bounds__(256)
void topk_x_kernel(const float* __restrict__ x, int* __restrict__ idx_out)
{
    __shared__ __align__(16) float pd[4][NPTS];
    __shared__ float ctr[4][3];
    const int blk = blockIdx.x;               // 4096 = 8 * 512
    const int b = blk >> 9;
    const int n0 = (blk & 511) << 2;
    const int tid = threadIdx.x;
    const float* base = x + (long)b * 3 * NPTS;

    if (tid < 16) {
        int w = tid >> 2, c = tid & 3;
        if (c < 3) ctr[w][c] = base[c * NPTS + n0 + w];
    }
    __syncthreads();

    for (int j = tid; j < NPTS; j += 256) {
        float v0 = base[j], v1 = base[NPTS + j], v2 = base[2 * NPTS + j];
        float sq = v0*v0 + v1*v1 + v2*v2;
#pragma unroll
        for (int w = 0; w < 4; ++w) {
            float d  = v0*ctr[w][0] + v1*ctr[w][1] + v2*ctr[w][2];
            float sc = ctr[w][0]*ctr[w][0] + ctr[w][1]*ctr[w][1] + ctr[w][2]*ctr[w][2];
            pd[w][j] = 2.f*d - sc - sq;
        }
    }
    __syncthreads();
    argmax20_reg(pd[tid >> 6], idx_out, (long)b * NPTS + n0 + (tid >> 6));
}

// ---------------------------------------------------------------------------
// Per-point squared norm over C channels at chanOff (order-matched).
// ---------------------------------------------------------------------------
template<int C>
__global__ __launch_bounds__(256)
void norm_kernel(const float* __restrict__ feat, int chanOff,
                 float* __restrict__ norms)
{
    int gid = blockIdx.x * 256 + threadIdx.x;   // 0..16383 = b*NPTS + n
    const float4* p = (const float4*)(feat + (long)gid * CATC + chanOff);
    float s = 0.f;
#pragma unroll
    for (int q = 0; q < C / 4; ++q) {
        float4 r = p[q];
        s += r.x*r.x; s += r.y*r.y; s += r.z*r.z; s += r.w*r.w;
    }
    norms[gid] = s;
}

// ---------------------------------------------------------------------------
// Layer 2-4 topk: 16 centers per block, 1024 threads; dot[16][2] accums.
// ---------------------------------------------------------------------------
template<int C>
__global__ __launch_bounds__(1024)
void topk_feat_kernel(const float* __restrict__ feat, int chanOff,
                      const float* __restrict__ norms,
                      int* __restrict__ idx_out)
{
    __shared__ __align__(16) float pd[16][NPTS];   // 128 KB
    const int blk = blockIdx.x;                    // 1024 = 8 * 128
    const int b = blk >> 7;
    const int n0 = (blk & 127) << 4;
    const int tid = threadIdx.x;                   // 0..1023
    const float* base = feat + (long)b * NPTS * CATC + chanOff;
    constexpr int Q = C / 4;

    const float4* c4p[16];
#pragma unroll
    for (int w = 0; w < 16; ++w)
        c4p[w] = (const float4*)(base + (long)(n0 + w) * CATC);

    float sqc[16];
#pragma unroll
    for (int w = 0; w < 16; ++w)
        sqc[w] = norms[(long)b * NPTS + n0 + w];   // uniform -> s_load

    const float* rowBase[2];
    float nrm[2];
#pragma unroll
    for (int k = 0; k < 2; ++k) {
        rowBase[k] = base + (long)(tid + 1024 * k) * CATC;
        nrm[k] = norms[(long)b * NPTS + tid + 1024 * k];
    }

    float dot[16][2];
#pragma unroll
    for (int w = 0; w < 16; ++w)
#pragma unroll
        for (int k = 0; k < 2; ++k) dot[w][k] = 0.f;

    for (int q = 0; q < Q; ++q) {
        float4 r[2];
#pragma unroll
        for (int k = 0; k < 2; ++k)
            r[k] = *(const float4*)(rowBase[k] + q * 4);
#pragma unroll
        for (int w = 0; w < 16; ++w) {
            float4 cw = c4p[w][q];    // block-uniform -> scalar load
#pragma unroll
            for (int k = 0; k < 2; ++k) {
                dot[w][k] += r[k].x * cw.x;
                dot[w][k] += r[k].y * cw.y;
                dot[w][k] += r[k].z * cw.z;
                dot[w][k] += r[k].w * cw.w;
            }
        }
    }

#pragma unroll
    for (int k = 0; k < 2; ++k)
#pragma unroll
        for (int w = 0; w < 16; ++w)
            pd[w][tid + 1024*k] = 2.f*dot[w][k] - sqc[w] - nrm[k];
    __syncthreads();
    argmax20_reg(pd[tid >> 6], idx_out, (long)b * NPTS + n0 + (tid >> 6));
}

// ---------------------------------------------------------------------------
// Layer-1 EdgeConv: x fp32 (B,3,N) -> feat ch 0..63 (fp32).
// ---------------------------------------------------------------------------
__global__ __launch_bounds__(64)
void edgeconv_x_kernel(const float* __restrict__ x, const int* __restrict__ idx,
                       const float* __restrict__ W, const float* __restrict__ g,
                       const float* __restrict__ bb, float* __restrict__ feat)
{
    __shared__ float ctr[3];
    __shared__ float nd[KNBR * 3];
    __shared__ int jj[KNBR];
    const int row = blockIdx.x;
    const int b = row >> 11, n = row & (NPTS - 1);
    const int tid = threadIdx.x;
    const float* base = x + (long)b * 3 * NPTS;
    if (tid < 3)    ctr[tid] = base[tid * NPTS + n];
    if (tid < KNBR) jj[tid]  = idx[(long)row * KNBR + tid];
    __syncthreads();
    if (tid < KNBR * 3) {
        int kk = tid / 3, c = tid - kk * 3;
        nd[tid] = base[c * NPTS + jj[kk]] - ctr[c];
    }
    __syncthreads();

    const float* wr = W + tid * 6;      // o = tid, W1 (64,6)
    float basev = wr[3]*ctr[0] + wr[4]*ctr[1] + wr[5]*ctr[2];
    float scale = g[tid] * rsqrtf(1.f + 1e-5f);
    float bias  = bb[tid];
    float m = -FLT_MAX;
#pragma unroll
    for (int kk = 0; kk < KNBR; ++kk) {
        float s = basev + wr[0]*nd[kk*3] + wr[1]*nd[kk*3+1] + wr[2]*nd[kk*3+2];
        m = fmaxf(m, lrelu(s * scale + bias));
    }
    feat[((long)b * NPTS + n) * CATC + tid] = m;
}

// ---------------------------------------------------------------------------
// GEMM path, kernel 1: GH[n][0:O] = W[:,0:C]·f(n), GH[n][O:2O] = W[:,C:2C]·f(n)
// ---------------------------------------------------------------------------
template<int C, int O>
__global__ __launch_bounds__(256)
void gemm_gh_kernel(const float* __restrict__ feat, int chanIn,
                    const float* __restrict__ W, float* __restrict__ GH)
{
    __shared__ __align__(16) float Ws[64][C + 4];
    __shared__ __align__(16) float Cs[32][C + 4];
    const int mt = blockIdx.x, ot = blockIdx.y;
    const int tid = threadIdx.x;
    const int ol = tid & 63, ng = tid >> 6;
    const int side = (ot * 64) >= O;   // 0 -> G (W[:,0:C]); 1 -> H (W[:,C:2C])

    for (int t = tid; t < 64 * (C / 4); t += 256) {
        int olr = t / (C / 4), q = t - olr * (C / 4);
        int o = ot * 64 + olr - (side ? O : 0);
        *(float4*)&Ws[olr][q * 4] =
            *(const float4*)&W[(long)o * 2 * C + (side ? C : 0) + q * 4];
    }
    for (int t = tid; t < 32 * (C / 4); t += 256) {
        int nl = t / (C / 4), q = t - nl * (C / 4);
        *(float4*)&Cs[nl][q * 4] =
            *(const float4*)&feat[(long)(mt * 32 + nl) * CATC + chanIn + q * 4];
    }
    __syncthreads();

    float acc[8];
#pragma unroll
    for (int i = 0; i < 8; ++i) acc[i] = 0.f;
    for (int k4 = 0; k4 < C / 4; ++k4) {
        float4 w = *(const float4*)&Ws[ol][k4 * 4];
#pragma unroll
        for (int i = 0; i < 8; ++i) {
            float4 c = *(const float4*)&Cs[ng * 8 + i][k4 * 4];
            acc[i] += w.x*c.x + w.y*c.y + w.z*c.z + w.w*c.w;
        }
    }
#pragma unroll
    for (int i = 0; i < 8; ++i)
        GH[(long)(mt * 32 + ng * 8 + i) * (2 * O) + ot * 64 + ol] = acc[i];
}

// ---------------------------------------------------------------------------
// GEMM path, kernel 2: per point n, m[o] = max_kk lrelu((H[n][o]-G[n][o]
//   + G[j_kk][o])*scale + bias); write feat[n][chanOut+o].
// ---------------------------------------------------------------------------
template<int O, int OPT>
__global__ __launch_bounds__(256)
void gathermax_kernel(const float* __restrict__ GH, const int* __restrict__ idx,
                      const float* __restrict__ g, const float* __restrict__ bb,
                      float* __restrict__ featOut, int chanOut)
{
    const int tid = threadIdx.x;
    const int row = blockIdx.x * 4 + (tid >> 6);   // b*NPTS + n
    const int lane = tid & 63;
    const long ghRow = (long)row * (2 * O);
    const long bBase = (long)(row & ~(NPTS - 1)) * (2 * O);
    const float inv = rsqrtf(1.f + 1e-5f);

    int j[KNBR];
#pragma unroll
    for (int i = 0; i < KNBR; ++i) j[i] = idx[(long)row * KNBR + i];

    float base2[OPT], m[OPT], scale[OPT], bias[OPT];
#pragma unroll
    for (int oi = 0; oi < OPT; ++oi) {
        int o = lane + 64 * oi;
        base2[oi] = GH[ghRow + O + o] - GH[ghRow + o];
        scale[oi] = g[o] * inv;
        bias[oi]  = bb[o];
        m[oi] = -FLT_MAX;
    }
#pragma unroll
    for (int kk = 0; kk < KNBR; ++kk) {
        const float* gr = GH + bBase + (long)j[kk] * (2 * O);
#pragma unroll
        for (int oi = 0; oi < OPT; ++oi) {
            float v = base2[oi] + gr[lane + 64 * oi];
            m[oi] = fmaxf(m[oi], lrelu(v * scale[oi] + bias[oi]));
        }
    }
#pragma unroll
    for (int oi = 0; oi < OPT; ++oi)
        featOut[(long)row * CATC + chanOut + lane + 64 * oi] = m[oi];
}

// ---------------------------------------------------------------------------
// Fallback (small ws): r14 edgeconv — 128 threads, 2 points per block.
// ---------------------------------------------------------------------------
template<int C, int OPT>
__global__ __launch_bounds__(128)
void edgeconv_feat_kernel(const float* __restrict__ featIn, int chanIn,
                          const int* __restrict__ idx,
                          const float* __restrict__ W, const float* __restrict__ g,
                          const float* __restrict__ bb,
                          float* __restrict__ featOut, int chanOut)
{
    __shared__ float ctr[2][C];
    __shared__ __align__(16) float nd[2][KNBR * C];
    __shared__ int jj[2][KNBR];
    const int blk = blockIdx.x;             // 8192 = 8 * 1024
    const int b = blk >> 10;
    const int n0 = (blk & 1023) << 1;
    const int tid = threadIdx.x;
    const int wv = tid >> 6, lane = tid & 63;
    const int n = n0 + wv;
    const long row = (long)b * NPTS + n;
    const float* base = featIn + (long)b * NPTS * CATC + chanIn;

    if (lane < KNBR) jj[wv][lane] = idx[row * KNBR + lane];
    for (int c = lane; c < C; c += 64) ctr[wv][c] = base[(long)n * CATC + c];
    __syncthreads();

    for (int t = lane; t < KNBR * (C / 4); t += 64) {
        int kk = t / (C / 4), q = t - kk * (C / 4);
        float4 r = ((const float4*)(base + (long)jj[wv][kk] * CATC))[q];
        float* dst = &nd[wv][kk * C + q * 4];
        const float* cc = &ctr[wv][q * 4];
        dst[0] = r.x - cc[0]; dst[1] = r.y - cc[1];
        dst[2] = r.z - cc[2]; dst[3] = r.w - cc[3];
    }
    __syncthreads();

    float acc[OPT][KNBR];
#pragma unroll
    for (int oi = 0; oi < OPT; ++oi) {
        const float* wr = W + (long)(lane + 64*oi) * 2 * C + C;
        float basev = 0.f;
#pragma unroll
        for (int c = 0; c < C; ++c) basev += wr[c] * ctr[wv][c];
#pragma unroll
        for (int kk = 0; kk < KNBR; ++kk) acc[oi][kk] = basev;
    }

    const float4* nd4 = (const float4*)nd[wv];
    for (int c4 = 0; c4 < C / 4; ++c4) {
        float4 w[OPT];
#pragma unroll
        for (int oi = 0; oi < OPT; ++oi) {
            const float* wp = W + (long)(lane + 64*oi) * 2 * C + c4 * 4;
            w[oi] = make_float4(wp[0], wp[1], wp[2], wp[3]);
        }
#pragma unroll
        for (int kk = 0; kk < KNBR; ++kk) {
            float4 d = nd4[kk * (C / 4) + c4];
#pragma unroll
            for (int oi = 0; oi < OPT; ++oi)
                acc[oi][kk] += w[oi].x*d.x + w[oi].y*d.y + w[oi].z*d.z + w[oi].w*d.w;
        }
    }

    const float inv = rsqrtf(1.f + 1e-5f);
#pragma unroll
    for (int oi = 0; oi < OPT; ++oi) {
        int o = lane + 64 * oi;
        float scale = g[o] * inv, bias = bb[o];
        float m = -FLT_MAX;
#pragma unroll
        for (int kk = 0; kk < KNBR; ++kk)
            m = fmaxf(m, lrelu(acc[oi][kk] * scale + bias));
        featOut[row * CATC + chanOut + o] = m;
    }
}

// ---------------------------------------------------------------------------
// x5 = lrelu(bn(W5 @ cat)) with fused pooling partials.
// r15 inner loop UNCHANGED (1 o x 8 n per thread, bit-identical FMA chain);
// only the grid is split: nt 8 -> 16 (block covers 64 o x 128 n, 4 subtiles
// of 32 n), doubling blocks 1024 -> 2048 to lift the grid-residency cap
// (occupancy was 26.8% with no VGPR/LDS limit binding). 16 partials/(b,o).
// ---------------------------------------------------------------------------
__global__ __launch_bounds__(256)
void x5_kernel(const float* __restrict__ feat, const float* __restrict__ W5,
               const float* __restrict__ g5, const float* __restrict__ b5,
               float* __restrict__ pmax, float* __restrict__ psum)
{
    __shared__ __align__(16) float Ws[64][36];
    __shared__ __align__(16) float Cs[32][36];
    __shared__ float red[64][8];
    const int tid = threadIdx.x;
    const int nt = blockIdx.x, ot = blockIdx.y, b = blockIdx.z;
    const int ol = tid & 63, ng = tid >> 6;
    const int o = ot * 64 + ol;
    const float scale = g5[o] * rsqrtf(1.f + 1e-5f);
    const float bias  = b5[o];

    float gmax = -FLT_MAX, gsum = 0.f;
    for (int s = 0; s < 4; ++s) {
        float acc[8];
#pragma unroll
        for (int i = 0; i < 8; ++i) acc[i] = 0.f;
        const int nBase = nt * 128 + s * 32;

        for (int kb = 0; kb < 16; ++kb) {
#pragma unroll
            for (int t = tid; t < 512; t += 256) {
                int olr = t >> 3, q = t & 7;
                *(float4*)&Ws[olr][q*4] =
                    *(const float4*)&W5[(long)(ot*64 + olr) * CATC + kb*32 + q*4];
            }
            {
                int nl = tid >> 3, q = tid & 7;
                *(float4*)&Cs[nl][q*4] =
                    *(const float4*)&feat[((long)b*NPTS + nBase + nl)*CATC + kb*32 + q*4];
            }
            __syncthreads();
#pragma unroll
            for (int k4 = 0; k4 < 8; ++k4) {
                float4 w = *(const float4*)&Ws[ol][k4*4];
#pragma unroll
                for (int i = 0; i < 8; ++i) {
                    float4 c4 = *(const float4*)&Cs[ng*8 + i][k4*4];
                    acc[i] += w.x*c4.x + w.y*c4.y + w.z*c4.z + w.w*c4.w;
                }
            }
            __syncthreads();
        }
#pragma unroll
        for (int i = 0; i < 8; ++i) {
            float v = lrelu(acc[i] * scale + bias);
            gmax = fmaxf(gmax, v);
            gsum += v;
        }
    }
    red[ol][ng]     = gmax;
    red[ol][4 + ng] = gsum;
    __syncthreads();
    if (tid < 64) {
        float m = red[tid][0], sm = red[tid][4];
#pragma unroll
        for (int w = 1; w < 4; ++w) { m = fmaxf(m, red[tid][w]); sm += red[tid][4 + w]; }
        long p = ((long)b * 1024 + ot * 64 + tid) * 16 + nt;
        pmax[p] = m; psum[p] = sm;
    }
}

// Reduce 16 partials per (b,o) -> xm/xa; write map2 (fp32) + map_ (fp32).
__global__ __launch_bounds__(256)
void reduce16_kernel(const float* __restrict__ pmax, const float* __restrict__ psum,
                     float* __restrict__ map2, float* __restrict__ out_map)
{
    int gid = blockIdx.x * 256 + threadIdx.x;   // 8192 = 8*1024
    int b = gid >> 10, o = gid & 1023;
    float m = -FLT_MAX, s = 0.f;
#pragma unroll
    for (int t = 0; t < 16; ++t) {
        m = fmaxf(m, pmax[(long)gid * 16 + t]);
        s += psum[(long)gid * 16 + t];
    }
    float xa = s * (1.f / NPTS);
    map2[(long)b * 2080 + o]        = m;
    map2[(long)b * 2080 + 1024 + o] = xa;
    out_map[(long)b * 2048 + o]        = m;
    out_map[(long)b * 2048 + 1024 + o] = xa;
}

// p1 = lrelu(bn(posefeat @ Wp.T + bp)) -> map2[:, 2048:2080]
__global__ void pose_kernel(const float* __restrict__ pf, const float* __restrict__ Wp,
                            const float* __restrict__ bp, const float* __restrict__ gp,
                            const float* __restrict__ bpb, float* __restrict__ map2)
{
    int t = threadIdx.x;
    if (t < 256) {
        int b = t >> 5, o = t & 31;
        float s = 0.f;
#pragma unroll
        for (int c = 0; c < 6; ++c) s += pf[b*6 + c] * Wp[o*6 + c];
        s += bp[o];
        s = s * (gp[o] * rsqrtf(1.f + 1e-5f)) + bpb[o];
        map2[(long)b * 2080 + 2048 + o] = lrelu(s);
    }
}

// Generic FC: one wave per (b,o). fp32 output.
__global__ __launch_bounds__(64)
void fc_kernel(const float* __restrict__ in, int inStride, int Kdim,
               const float* __restrict__ W, const float* __restrict__ bias,
               const float* __restrict__ g, const float* __restrict__ bbn,
               int Nout, float* __restrict__ outF, int outStride)
{
    int bo = blockIdx.x;
    int b = bo / Nout, o = bo - b * Nout;
    int lane = threadIdx.x;
    const float* inr = in + (long)b * inStride;
    const float* wr  = W + (long)o * Kdim;
    float s = 0.f;
    for (int c = lane; c < Kdim; c += 64) s += inr[c] * wr[c];
#pragma unroll
    for (int off = 32; off; off >>= 1) s += __shfl_down(s, off);
    if (lane == 0) {
        s += bias[o];
        if (g) {
            s = s * (g[o] * rsqrtf(1.f + 1e-5f)) + bbn[o];
            s = lrelu(s);
        }
        outF[(long)b * outStride + o] = s;
    }
}

extern "C" void kernel_launch(void* const* d_in, const int* in_sizes, int n_in,
                              void* d_out, int out_size, void* d_ws, size_t ws_size,
                              hipStream_t stream)
{
    const float* x   = (const float*)d_in[0];
    const float* pf  = (const float*)d_in[1];
    const float *W1 = (const float*)d_in[2],  *g1 = (const float*)d_in[3],  *b1 = (const float*)d_in[4];
    const float *W2 = (const float*)d_in[5],  *g2 = (const float*)d_in[6],  *b2 = (const float*)d_in[7];
    const float *W3 = (const float*)d_in[8],  *g3 = (const float*)d_in[9],  *b3 = (const float*)d_in[10];
    const float *W4 = (const float*)d_in[11], *g4 = (const float*)d_in[12], *b4 = (const float*)d_in[13];
    const float *W5 = (const float*)d_in[14], *g5 = (const float*)d_in[15], *b5 = (const float*)d_in[16];
    const float *Wp = (const float*)d_in[17], *bp = (const float*)d_in[18];
    const float *gp = (const float*)d_in[19], *bpb = (const float*)d_in[20];
    const float *WL1 = (const float*)d_in[21], *bL1 = (const float*)d_in[22];
    const float *g6  = (const float*)d_in[23], *b6  = (const float*)d_in[24];
    const float *WL2 = (const float*)d_in[25], *bL2 = (const float*)d_in[26];
    const float *g7  = (const float*)d_in[27], *b7  = (const float*)d_in[28];
    const float *WL3 = (const float*)d_in[29], *bL3 = (const float*)d_in[30];

    // workspace layout (bytes):
    //   feat  @ 0          : 33,554,432
    //   idx   @ 33554432   :  1,310,720
    //   map2  @ 35389440   :     66,560
    //   h1/h2/norms as before
    //   GH    @ 35546112   : 33,554,432 (edgeconv phase)
    //   pmax  @ 35546112   : 524,288  \ overlap GH — x5/pooling run AFTER
    //   psum  @ 36070400   : 524,288  / gathermax has consumed GH
    char* wsb = (char*)d_ws;
    float* feat  = (float*)wsb;
    int*   idx   = (int*)(wsb + 33554432);
    float* map2  = (float*)(wsb + 35389440);
    float* h1    = (float*)(wsb + 35456000);
    float* h2    = (float*)(wsb + 35472384);
    float* norms = (float*)(wsb + 35480576);
    float* GH    = (float*)(wsb + 35546112);
    float* pmax  = (float*)(wsb + 35546112);           // reuses GH region
    float* psum  = (float*)(wsb + 35546112 + 524288);
    const bool gemmPath = (ws_size >= (size_t)35546112 + 33554432);

    // FP32 output, return order: logits (8,40) then map_ (8,2048).
    float* out        = (float*)d_out;
    float* out_logits = out;
    float* out_map    = out + 320;

    const int rows = 8 * NPTS;      // 16384
    const int tkblk16 = rows / 16;  // 1024 (16 centers per topk block)
    const int gmblk   = rows / 4;   // 4096 (4 points per gathermax block)

    // layer 1: C=3 -> 64 (feat ch 0..63)
    topk_x_kernel<<<rows / 4, 256, 0, stream>>>(x, idx);
    edgeconv_x_kernel<<<rows, 64, 0, stream>>>(x, idx, W1, g1, b1, feat);

    // layer 2: C=64 (ch 0..63) -> 64 (ch 64..127)
    norm_kernel<64><<<64, 256, 0, stream>>>(feat, 0, norms);
    topk_feat_kernel<64><<<tkblk16, 1024, 0, stream>>>(feat, 0, norms, idx);
    if (gemmPath) {
        gemm_gh_kernel<64, 64><<<dim3(512, 2), 256, 0, stream>>>(feat, 0, W2, GH);
        gathermax_kernel<64, 1><<<gmblk, 256, 0, stream>>>(GH, idx, g2, b2, feat, 64);
    } else {
        edgeconv_feat_kernel<64, 1><<<rows / 2, 128, 0, stream>>>(feat, 0, idx, W2, g2, b2, feat, 64);
    }

    // layer 3: C=64 (ch 64..127) -> 128 (ch 128..255)
    norm_kernel<64><<<64, 256, 0, stream>>>(feat, 64, norms);
    topk_feat_kernel<64><<<tkblk16, 1024, 0, stream>>>(feat, 64, norms, idx);
    if (gemmPath) {
        gemm_gh_kernel<64, 128><<<dim3(512, 4), 256, 0, stream>>>(feat, 64, W3, GH);
        gathermax_kernel<128, 2><<<gmblk, 256, 0, stream>>>(GH, idx, g3, b3, feat, 128);
    } else {
        edgeconv_feat_kernel<64, 2><<<rows / 2, 128, 0, stream>>>(feat, 64, idx, W3, g3, b3, feat, 128);
    }

    // layer 4: C=128 (ch 128..255) -> 256 (ch 256..511)
    norm_kernel<128><<<64, 256, 0, stream>>>(feat, 128, norms);
    topk_feat_kernel<128><<<tkblk16, 1024, 0, stream>>>(feat, 128, norms, idx);
    if (gemmPath) {
        gemm_gh_kernel<128, 256><<<dim3(512, 8), 256, 0, stream>>>(feat, 128, W4, GH);
        gathermax_kernel<256, 4><<<gmblk, 256, 0, stream>>>(GH, idx, g4, b4, feat, 256);
    } else {
        edgeconv_feat_kernel<128, 4><<<rows / 2, 128, 0, stream>>>(feat, 128, idx, W4, g4, b4, feat, 256);
    }

    // x5 + pooling: grid (16 nt of 128 n, 16 ot of 64 o, 8 b) = 2048 blocks
    dim3 g5grid(16, 16, 8);
    x5_kernel<<<g5grid, 256, 0, stream>>>(feat, W5, g5, b5, pmax, psum);
    reduce16_kernel<<<32, 256, 0, stream>>>(pmax, psum, map2, out_map);

    // head
    pose_kernel<<<1, 256, 0, stream>>>(pf, Wp, bp, gp, bpb, map2);
    fc_kernel<<<8 * 512, 64, 0, stream>>>(map2, 2080, 2080, WL1, bL1, g6, b6, 512, h1, 512);
    fc_kernel<<<8 * 256, 64, 0, stream>>>(h1, 512, 512, WL2, bL2, g7, b7, 256, h2, 256);
    fc_kernel<<<8 * 40, 64, 0, stream>>>(h2, 256, 256, WL3, bL3, nullptr, nullptr, 40, out_logits, 40);
}